// Round 6
// baseline (390.150 us; speedup 1.0000x reference)
//
#include <hip/hip_runtime.h>
#include <hip/hip_bf16.h>
#include <math.h>

typedef __bf16 bf16;
typedef bf16 bf16x8 __attribute__((ext_vector_type(8)));
typedef bf16 bf16x4v __attribute__((ext_vector_type(4)));
typedef float f32x4 __attribute__((ext_vector_type(4)));
typedef _Float16 f16;
typedef f16 f16x4 __attribute__((ext_vector_type(4)));

#define GLD16(g, l) __builtin_amdgcn_global_load_lds(                          \
    (__attribute__((address_space(1))) void*)(g),                              \
    (__attribute__((address_space(3))) void*)(l), 16, 0, 0)

#define MFMA16(a, b, c) __builtin_amdgcn_mfma_f32_16x16x32_bf16((a), (b), (c), 0, 0, 0)

// NOTE: __has_builtin(__builtin_amdgcn_*) is FALSE in the HIP host pass even
// though calls compile (aux-target builtins), AND the host pass type-checks
// __global__ bodies. Fallback must be a __host__ __device__ parseable stub.
#if __has_builtin(__builtin_amdgcn_mfma_f32_16x16x16_f16)
#define MFMA16F16(a, b, c) __builtin_amdgcn_mfma_f32_16x16x16_f16((a), (b), (c), 0, 0, 0)
#elif __has_builtin(__builtin_amdgcn_mfma_f32_16x16x16f16)
#define MFMA16F16(a, b, c) __builtin_amdgcn_mfma_f32_16x16x16f16((a), (b), (c), 0, 0, 0)
#else
__host__ __device__ static inline f32x4 MFMA16F16(f16x4 a, f16x4 b, f32x4 c) { return c; }
#endif

// ---------------- cast f32 -> bf16 (vectorized) ----------------
__global__ void cast_f32_bf16(const float* __restrict__ in, bf16* __restrict__ out, int n4) {
  int i = blockIdx.x * blockDim.x + threadIdx.x;
  if (i < n4) {
    float4 v = ((const float4*)in)[i];
    bf16x4v o;
    o.x = (bf16)v.x; o.y = (bf16)v.y; o.z = (bf16)v.z; o.w = (bf16)v.w;
    ((bf16x4v*)out)[i] = o;
  }
}

// ---------------- transpose + cast + scale: out[off + c][r] = in[r][c]*scale ----------------
__global__ void transpose_cast(const float* __restrict__ in, bf16* __restrict__ out,
                               int colsIn, int outStride, int outRowOff, float scale) {
  __shared__ float t[32][33];
  int c0 = blockIdx.x * 32, r0 = blockIdx.y * 32;
  int tx = threadIdx.x, ty = threadIdx.y;  // block (32,8)
  #pragma unroll
  for (int i = 0; i < 32; i += 8)
    t[ty + i][tx] = in[(size_t)(r0 + ty + i) * colsIn + (c0 + tx)];
  __syncthreads();
  #pragma unroll
  for (int i = 0; i < 32; i += 8)
    out[(size_t)(outRowOff + c0 + ty + i) * outStride + (r0 + tx)] = (bf16)(t[tx][ty + i] * scale);
}

// ---------------- V -> V^T global f16: Vg[(b*4+kvh)][d][n] = (f16)QKV[b*2048+n][2560+kvh*128+d]
__global__ void transpose_v(const bf16* __restrict__ QKV, f16* __restrict__ Vg) {
  __shared__ bf16 t[32][34];
  int n0 = blockIdx.x * 32, d0 = blockIdx.y * 32;
  int bk = blockIdx.z;
  int b = bk >> 2, kvh = bk & 3;
  const bf16* src = QKV + (size_t)b * 2048 * 3072 + 2560 + kvh * 128;
  f16* dst = Vg + (size_t)bk * 128 * 2048;
  int tx = threadIdx.x, ty = threadIdx.y;  // block (32,8)
  #pragma unroll
  for (int i = 0; i < 32; i += 8)
    t[ty + i][tx] = src[(size_t)(n0 + ty + i) * 3072 + (d0 + tx)];
  __syncthreads();
  #pragma unroll
  for (int i = 0; i < 32; i += 8)
    dst[(size_t)(d0 + ty + i) * 2048 + (n0 + tx)] = (f16)(float)t[tx][ty + i];
}

// ---------------- m97-style GEMM: A[M][K] bf16, Bt[N][K] bf16 -> C[M][N] ----------------
template <typename OutT>
__global__ __launch_bounds__(256, 2) void gemm_bt(const bf16* __restrict__ A,
                                                  const bf16* __restrict__ Bt,
                                                  OutT* __restrict__ C,
                                                  int M, int N, int K) {
  __shared__ __attribute__((aligned(16))) bf16 As[128 * 32];
  __shared__ __attribute__((aligned(16))) bf16 Bs[128 * 32];
  const int tid = threadIdx.x;
  const int lane = tid & 63;
  const int wave = tid >> 6;
  const int wm = wave >> 1, wn = wave & 1;
  const int l15 = lane & 15, quad = lane >> 4;
  const int rowBase = blockIdx.y * 128;
  const int colBase = blockIdx.x * 128;

  f32x4 acc[4][4] = {};

  const int cb0 = wave * 64;
  const int c0 = cb0 + lane;
  const int c1 = c0 + 256;
  const bf16* a0 = A + (size_t)(rowBase + (c0 >> 2)) * K + (c0 & 3) * 8;
  const bf16* a1 = A + (size_t)(rowBase + (c1 >> 2)) * K + (c1 & 3) * 8;
  const bf16* b0 = Bt + (size_t)(colBase + (c0 >> 2)) * K + (c0 & 3) * 8;
  const bf16* b1 = Bt + (size_t)(colBase + (c1 >> 2)) * K + (c1 & 3) * 8;
  bf16* lA0 = &As[cb0 * 8];
  bf16* lA1 = &As[(cb0 + 256) * 8];
  bf16* lB0 = &Bs[cb0 * 8];
  bf16* lB1 = &Bs[(cb0 + 256) * 8];

  for (int k0 = 0; k0 < K; k0 += 32) {
    GLD16(a0 + k0, lA0);
    GLD16(a1 + k0, lA1);
    GLD16(b0 + k0, lB0);
    GLD16(b1 + k0, lB1);
    __syncthreads();
    bf16x8 af[4], bfr[4];
    #pragma unroll
    for (int i = 0; i < 4; i++)
      af[i] = *(const bf16x8*)&As[(wm * 64 + i * 16 + l15) * 32 + quad * 8];
    #pragma unroll
    for (int i = 0; i < 4; i++)
      bfr[i] = *(const bf16x8*)&Bs[(wn * 64 + i * 16 + l15) * 32 + quad * 8];
    #pragma unroll
    for (int i = 0; i < 4; i++)
      #pragma unroll
      for (int j = 0; j < 4; j++)
        acc[i][j] = MFMA16(af[i], bfr[j], acc[i][j]);
    __syncthreads();
  }

  #pragma unroll
  for (int i = 0; i < 4; i++) {
    int row = rowBase + wm * 64 + i * 16 + quad * 4;
    #pragma unroll
    for (int j = 0; j < 4; j++) {
      int col = colBase + wn * 64 + j * 16 + l15;
      #pragma unroll
      for (int r = 0; r < 4; r++)
        C[(size_t)(row + r) * N + col] = (OutT)acc[i][j][r];
    }
  }
}

// ---------------- flash GQA v4: transposed scores AND transposed O ----------------
// S^T = K·Q^T : C-layout col(l15)=q-row, row(quad*4+r)=key -> scalar softmax stats.
// PV computed as O^T = V^T·P^T (pa reused as B-operand, vf as A-operand), so O^T's
// C-layout also has col(l15)=q-row: alpha/linv apply as per-lane scalars. (R5 bug:
// computing O=P·V puts q-row on quad*4+r, mismatching the l15-indexed stats.)
#define MASKV (-1e30f)

__global__ __launch_bounds__(256, 3) void gqa_attn(const bf16* __restrict__ QKV,
                                                   const f16* __restrict__ Vg,
                                                   bf16* __restrict__ Obf) {
  __shared__ __attribute__((aligned(16))) bf16 Kl[64 * 128];  // [key][hd], chunk8 c'=c^(key&7)
  __shared__ __attribute__((aligned(16))) f16  Vt[128 * 64];  // [d][key], granule8 s=(g+(d&7))&7

  const int tid = threadIdx.x;
  const int lane = tid & 63;
  const int wave = tid >> 6;
  const int l15 = lane & 15, quad = lane >> 4;

  // heavy-first: qt=15 blocks dispatched first -> better tail balance
  int bi = blockIdx.x;
  int qt = 15 - (bi >> 5);
  int bh = bi & 31;
  int b = bh >> 4, h = bh & 15, kvh = h >> 2;
  int q0 = qt * 128;

  const size_t rs = 3072;
  const bf16* Qb  = QKV + (size_t)b * 2048 * rs + h * 128;
  const bf16* Kb  = QKV + (size_t)b * 2048 * rs + 2048 + kvh * 128;
  const f16*  Vgb = Vg + (size_t)(b * 4 + kvh) * 128 * 2048;

  // Q fragments (pre-scaled by SCALE*log2e): B-operand, n=q-row=l15, k=hd
  bf16x8 qf[2][4];
  #pragma unroll
  for (int mt = 0; mt < 2; mt++) {
    int row = q0 + wave * 32 + mt * 16 + l15;
    #pragma unroll
    for (int ks = 0; ks < 4; ks++)
      qf[mt][ks] = *(const bf16x8*)&Qb[(size_t)row * rs + ks * 32 + quad * 8];
  }

  // DMA staging pointers (swizzle folded into global address, LDS dest = base+lane*16)
  const bf16* kp[4]; const f16* vp[4];
  bf16* kl[4]; f16* vl[4];
  #pragma unroll
  for (int t = 0; t < 4; t++) {
    int keyl = wave * 16 + t * 4 + (lane >> 4);
    int ck = (lane & 15) ^ (4 * (t & 1) + (lane >> 4));  // keyl&7 = 4*(t&1)+(lane>>4)
    kp[t] = Kb + (size_t)keyl * rs + ck * 8;
    kl[t] = &Kl[(wave * 16 + t * 4) * 128];
    int dl = wave * 32 + t * 8 + (lane >> 3);
    int g = ((lane & 7) - (dl & 7)) & 7;  // source 8-key granule for LDS slot lane&7
    vp[t] = Vgb + (size_t)dl * 2048 + g * 8;
    vl[t] = &Vt[(wave * 32 + t * 8) * 64];
  }

  f32x4 oacc[2][8] = {};   // O^T: [mt][no], col=l15=qrow, row=quad*4+r -> d=no*16+quad*4+r
  float mst[2] = {MASKV, MASKV}, lst[2] = {0.f, 0.f};

  const int nkt = 2 * qt + 2;
  const int myrow_hi = q0 + wave * 32 + 31;
  for (int kt = 0; kt < nkt; kt++) {
    const int k0 = kt * 64;
    __syncthreads();  // previous tile fully consumed
    #pragma unroll
    for (int t = 0; t < 4; t++) { GLD16(kp[t], kl[t]); kp[t] += 64 * rs; }
    #pragma unroll
    for (int t = 0; t < 4; t++) { GLD16(vp[t], vl[t]); vp[t] += 64; }
    __syncthreads();  // vmcnt drained before barrier -> tiles ready

    if (k0 > myrow_hi) continue;  // wave fully masked

    // S^T = K·Q^T : s[mt][nt], nt = key16 chunk
    f32x4 s[2][4] = {};
    #pragma unroll
    for (int ks = 0; ks < 4; ks++) {
      #pragma unroll
      for (int nt = 0; nt < 4; nt++) {
        bf16x8 kf = *(const bf16x8*)&Kl[(nt * 16 + l15) * 128 +
                                        (((ks * 4 + quad) ^ (l15 & 7)) * 8)];
        s[0][nt] = MFMA16(kf, qf[0][ks], s[0][nt]);
        s[1][nt] = MFMA16(kf, qf[1][ks], s[1][nt]);
      }
    }
    // causal mask: key > qrow (only last two tiles touch the diagonal)
    if (kt >= nkt - 2) {
      #pragma unroll
      for (int mt = 0; mt < 2; mt++) {
        int qrow = q0 + wave * 32 + mt * 16 + l15;
        #pragma unroll
        for (int nt = 0; nt < 4; nt++) {
          int keyb = k0 + nt * 16 + quad * 4;
          #pragma unroll
          for (int r = 0; r < 4; r++)
            if (keyb + r > qrow) s[mt][nt][r] = MASKV;
        }
      }
    }
    // online softmax: per-lane scalar stats (lane owns q-row = l15 per mt);
    // after xor-16/32 reduction, stats are uniform across the 4 quads of a q-row.
    f16x4 pa[2][4];
    #pragma unroll
    for (int mt = 0; mt < 2; mt++) {
      float mloc = MASKV;
      #pragma unroll
      for (int nt = 0; nt < 4; nt++)
        #pragma unroll
        for (int r = 0; r < 4; r++) mloc = fmaxf(mloc, s[mt][nt][r]);
      mloc = fmaxf(mloc, __shfl_xor(mloc, 16));
      mloc = fmaxf(mloc, __shfl_xor(mloc, 32));
      float mnew = fmaxf(mst[mt], mloc);
      float alpha = exp2f(mst[mt] - mnew);
      float rsum = 0.f;
      #pragma unroll
      for (int nt = 0; nt < 4; nt++)
        #pragma unroll
        for (int r = 0; r < 4; r++) {
          float p = exp2f(s[mt][nt][r] - mnew);
          s[mt][nt][r] = p;
          rsum += p;
        }
      rsum += __shfl_xor(rsum, 16);
      rsum += __shfl_xor(rsum, 32);
      lst[mt] = lst[mt] * alpha + rsum;
      mst[mt] = mnew;
      #pragma unroll
      for (int no = 0; no < 8; no++)
        #pragma unroll
        for (int r = 0; r < 4; r++) oacc[mt][no][r] *= alpha;  // col=l15=qrow: scalar ok
      #pragma unroll
      for (int nt = 0; nt < 4; nt++) {
        f16x4 p4;
        #pragma unroll
        for (int r = 0; r < 4; r++) p4[r] = (f16)s[mt][nt][r];
        pa[mt][nt] = p4;
      }
    }
    // O^T += V^T·P^T : A = vf (V^T[d=no*16+l15][key=quad*4+i]), B = pa
    // (P^T[k=quad*4+r][n=l15]) -> D[m=d][n=qrow], col=l15=qrow matches stats.
    #pragma unroll
    for (int nt = 0; nt < 4; nt++) {
      #pragma unroll
      for (int no = 0; no < 8; no++) {
        f16x4 vf = *(const f16x4*)&Vt[(no * 16 + l15) * 64 +
                                      (((nt * 4 + quad) + 2 * (l15 & 7)) & 15) * 4];
        oacc[0][no] = MFMA16F16(vf, pa[0][nt], oacc[0][no]);
        oacc[1][no] = MFMA16F16(vf, pa[1][nt], oacc[1][no]);
      }
    }
  }

  // epilogue: O^T C-layout -> lane owns q-row = l15; d = no*16 + quad*4 + r
  #pragma unroll
  for (int mt = 0; mt < 2; mt++) {
    float linv = 1.0f / lst[mt];
    int qrow = q0 + wave * 32 + mt * 16 + l15;
    bf16* orow = Obf + (size_t)(b * 2048 + qrow) * 2048 + h * 128 + quad * 4;
    #pragma unroll
    for (int no = 0; no < 8; no++) {
      bf16x4v o4;
      #pragma unroll
      for (int r = 0; r < 4; r++) o4[r] = (bf16)(oacc[mt][no][r] * linv);
      *(bf16x4v*)(orow + no * 16) = o4;
    }
  }
}

extern "C" void kernel_launch(void* const* d_in, const int* in_sizes, int n_in,
                              void* d_out, int out_size, void* d_ws, size_t ws_size,
                              hipStream_t stream) {
  const float* x  = (const float*)d_in[0];
  // d_in[1] = mask: always causal tril; handled analytically.
  const float* Wq = (const float*)d_in[2];
  const float* Wk = (const float*)d_in[3];
  const float* Wv = (const float*)d_in[4];
  const float* Wo = (const float*)d_in[5];
  float* out = (float*)d_out;

  // workspace layout (2-byte elements)
  bf16* Xb    = (bf16*)d_ws;           // 4096x2048
  bf16* Wqkvt = Xb + 8388608;          // 3072x2048 (transposed, fused Q|K|V)
  bf16* Wot   = Wqkvt + 6291456;       // 2048x2048 (transposed)
  bf16* QKV   = Wot + 4194304;         // 4096x3072
  bf16* Obf   = QKV + 12582912;        // 4096x2048
  f16*  Vg    = (f16*)(Obf + 8388608); // 8 x 128 x 2048 (V^T per (b,kvh), f16)
  // total 83,886,080 bytes

  const float qscale = (float)(0.08838834764831845 * 1.4426950408889634);

  cast_f32_bf16<<<8192, 256, 0, stream>>>(x, Xb, 2097152);
  dim3 tb(32, 8);
  transpose_cast<<<dim3(64, 64), tb, 0, stream>>>(Wq, Wqkvt, 2048, 2048, 0, qscale);
  transpose_cast<<<dim3(16, 64), tb, 0, stream>>>(Wk, Wqkvt, 512, 2048, 2048, 1.0f);
  transpose_cast<<<dim3(16, 64), tb, 0, stream>>>(Wv, Wqkvt, 512, 2048, 2560, 1.0f);
  transpose_cast<<<dim3(64, 64), tb, 0, stream>>>(Wo, Wot, 2048, 2048, 0, 1.0f);

  gemm_bt<bf16><<<dim3(24, 32), 256, 0, stream>>>(Xb, Wqkvt, QKV, 4096, 3072, 2048);
  transpose_v<<<dim3(64, 4, 8), tb, 0, stream>>>(QKV, Vg);
  gqa_attn<<<512, 256, 0, stream>>>(QKV, Vg, Obf);
  gemm_bt<float><<<dim3(16, 32), 256, 0, stream>>>(Obf, Wot, out, 4096, 2048, 2048);
}

// Round 7
// 389.063 us; speedup vs baseline: 1.0028x; 1.0028x over previous
//
#include <hip/hip_runtime.h>
#include <hip/hip_bf16.h>
#include <math.h>

typedef __bf16 bf16;
typedef bf16 bf16x8 __attribute__((ext_vector_type(8)));
typedef bf16 bf16x4v __attribute__((ext_vector_type(4)));
typedef float f32x4 __attribute__((ext_vector_type(4)));
typedef _Float16 f16;
typedef f16 f16x4 __attribute__((ext_vector_type(4)));

#define GLD16(g, l) __builtin_amdgcn_global_load_lds(                          \
    (__attribute__((address_space(1))) void*)(g),                              \
    (__attribute__((address_space(3))) void*)(l), 16, 0, 0)

#define MFMA16(a, b, c) __builtin_amdgcn_mfma_f32_16x16x32_bf16((a), (b), (c), 0, 0, 0)

// NOTE: __has_builtin(__builtin_amdgcn_*) is FALSE in the HIP host pass even
// though calls compile (aux-target builtins), AND the host pass type-checks
// __global__ bodies. Fallback must be a __host__ __device__ parseable stub.
#if __has_builtin(__builtin_amdgcn_mfma_f32_16x16x16_f16)
#define MFMA16F16(a, b, c) __builtin_amdgcn_mfma_f32_16x16x16_f16((a), (b), (c), 0, 0, 0)
#elif __has_builtin(__builtin_amdgcn_mfma_f32_16x16x16f16)
#define MFMA16F16(a, b, c) __builtin_amdgcn_mfma_f32_16x16x16f16((a), (b), (c), 0, 0, 0)
#else
__host__ __device__ static inline f32x4 MFMA16F16(f16x4 a, f16x4 b, f32x4 c) { return c; }
#endif

// ---------------- cast f32 -> bf16 (vectorized) ----------------
__global__ void cast_f32_bf16(const float* __restrict__ in, bf16* __restrict__ out, int n4) {
  int i = blockIdx.x * blockDim.x + threadIdx.x;
  if (i < n4) {
    float4 v = ((const float4*)in)[i];
    bf16x4v o;
    o.x = (bf16)v.x; o.y = (bf16)v.y; o.z = (bf16)v.z; o.w = (bf16)v.w;
    ((bf16x4v*)out)[i] = o;
  }
}

// ---------------- transpose + cast + scale: out[off + c][r] = in[r][c]*scale ----------------
__global__ void transpose_cast(const float* __restrict__ in, bf16* __restrict__ out,
                               int colsIn, int outStride, int outRowOff, float scale) {
  __shared__ float t[32][33];
  int c0 = blockIdx.x * 32, r0 = blockIdx.y * 32;
  int tx = threadIdx.x, ty = threadIdx.y;  // block (32,8)
  #pragma unroll
  for (int i = 0; i < 32; i += 8)
    t[ty + i][tx] = in[(size_t)(r0 + ty + i) * colsIn + (c0 + tx)];
  __syncthreads();
  #pragma unroll
  for (int i = 0; i < 32; i += 8)
    out[(size_t)(outRowOff + c0 + ty + i) * outStride + (r0 + tx)] = (bf16)(t[tx][ty + i] * scale);
}

// ---------------- V -> V^T global f16: Vg[(b*4+kvh)][d][n] = (f16)QKV[b*2048+n][2560+kvh*128+d]
__global__ void transpose_v(const bf16* __restrict__ QKV, f16* __restrict__ Vg) {
  __shared__ bf16 t[32][34];
  int n0 = blockIdx.x * 32, d0 = blockIdx.y * 32;
  int bk = blockIdx.z;
  int b = bk >> 2, kvh = bk & 3;
  const bf16* src = QKV + (size_t)b * 2048 * 3072 + 2560 + kvh * 128;
  f16* dst = Vg + (size_t)bk * 128 * 2048;
  int tx = threadIdx.x, ty = threadIdx.y;  // block (32,8)
  #pragma unroll
  for (int i = 0; i < 32; i += 8)
    t[ty + i][tx] = src[(size_t)(n0 + ty + i) * 3072 + (d0 + tx)];
  __syncthreads();
  #pragma unroll
  for (int i = 0; i < 32; i += 8)
    dst[(size_t)(d0 + ty + i) * 2048 + (n0 + tx)] = (f16)(float)t[tx][ty + i];
}

// ---------------- m97-style GEMM: A[M][K] bf16, Bt[N][K] bf16 -> C[M][N] ----------------
template <typename OutT>
__global__ __launch_bounds__(256, 2) void gemm_bt(const bf16* __restrict__ A,
                                                  const bf16* __restrict__ Bt,
                                                  OutT* __restrict__ C,
                                                  int M, int N, int K) {
  __shared__ __attribute__((aligned(16))) bf16 As[128 * 32];
  __shared__ __attribute__((aligned(16))) bf16 Bs[128 * 32];
  const int tid = threadIdx.x;
  const int lane = tid & 63;
  const int wave = tid >> 6;
  const int wm = wave >> 1, wn = wave & 1;
  const int l15 = lane & 15, quad = lane >> 4;
  const int rowBase = blockIdx.y * 128;
  const int colBase = blockIdx.x * 128;

  f32x4 acc[4][4] = {};

  const int cb0 = wave * 64;
  const int c0 = cb0 + lane;
  const int c1 = c0 + 256;
  const bf16* a0 = A + (size_t)(rowBase + (c0 >> 2)) * K + (c0 & 3) * 8;
  const bf16* a1 = A + (size_t)(rowBase + (c1 >> 2)) * K + (c1 & 3) * 8;
  const bf16* b0 = Bt + (size_t)(colBase + (c0 >> 2)) * K + (c0 & 3) * 8;
  const bf16* b1 = Bt + (size_t)(colBase + (c1 >> 2)) * K + (c1 & 3) * 8;
  bf16* lA0 = &As[cb0 * 8];
  bf16* lA1 = &As[(cb0 + 256) * 8];
  bf16* lB0 = &Bs[cb0 * 8];
  bf16* lB1 = &Bs[(cb0 + 256) * 8];

  for (int k0 = 0; k0 < K; k0 += 32) {
    GLD16(a0 + k0, lA0);
    GLD16(a1 + k0, lA1);
    GLD16(b0 + k0, lB0);
    GLD16(b1 + k0, lB1);
    __syncthreads();
    bf16x8 af[4], bfr[4];
    #pragma unroll
    for (int i = 0; i < 4; i++)
      af[i] = *(const bf16x8*)&As[(wm * 64 + i * 16 + l15) * 32 + quad * 8];
    #pragma unroll
    for (int i = 0; i < 4; i++)
      bfr[i] = *(const bf16x8*)&Bs[(wn * 64 + i * 16 + l15) * 32 + quad * 8];
    #pragma unroll
    for (int i = 0; i < 4; i++)
      #pragma unroll
      for (int j = 0; j < 4; j++)
        acc[i][j] = MFMA16(af[i], bfr[j], acc[i][j]);
    __syncthreads();
  }

  #pragma unroll
  for (int i = 0; i < 4; i++) {
    int row = rowBase + wm * 64 + i * 16 + quad * 4;
    #pragma unroll
    for (int j = 0; j < 4; j++) {
      int col = colBase + wn * 64 + j * 16 + l15;
      #pragma unroll
      for (int r = 0; r < 4; r++)
        C[(size_t)(row + r) * N + col] = (OutT)acc[i][j][r];
    }
  }
}

// ---------------- flash GQA v5 ----------------
// S^T = K·Q^T : C-layout col(l15)=q-row -> scalar softmax stats (xor 16/32 reduce).
// PV: O = P·V with P (A-frag, m=qrow on l15) straight from registers; O's C-layout
// has q-row on quad*4+r, so alpha/linv are redistributed with 4 __shfl's (stats are
// quad-uniform, lanes 0..15 are valid sources). Coalesced row-major epilogue.
#define MASKV (-1e30f)

__global__ __launch_bounds__(256, 3) void gqa_attn(const bf16* __restrict__ QKV,
                                                   const f16* __restrict__ Vg,
                                                   bf16* __restrict__ Obf) {
  __shared__ __attribute__((aligned(16))) bf16 Kl[64 * 128];  // [key][hd], chunk8 c'=c^(key&7)
  __shared__ __attribute__((aligned(16))) f16  Vt[128 * 64];  // [d][key], granule8 s=(g+(d&7))&7

  const int tid = threadIdx.x;
  const int lane = tid & 63;
  const int wave = tid >> 6;
  const int l15 = lane & 15, quad = lane >> 4;

  // balanced pairing (R2): blocks i and i+256 co-resident on a CU -> 34 tiles/CU.
  // (R6's heavy-first qt=15-(bi>>5) gave 48 vs 20 tile-units across CUs — 1.4x tail.)
  int bi = blockIdx.x;
  int bh = bi & 31;
  int jj = (bi & 255) >> 5;
  int qt = (bi < 256) ? (8 + jj) : (7 - jj);
  int b = bh >> 4, h = bh & 15, kvh = h >> 2;
  int q0 = qt * 128;

  const size_t rs = 3072;
  const bf16* Qb  = QKV + (size_t)b * 2048 * rs + h * 128;
  const bf16* Kb  = QKV + (size_t)b * 2048 * rs + 2048 + kvh * 128;
  const f16*  Vgb = Vg + (size_t)(b * 4 + kvh) * 128 * 2048;

  // Q fragments (pre-scaled by SCALE*log2e): B-operand, n=q-row=l15, k=hd
  bf16x8 qf[2][4];
  #pragma unroll
  for (int mt = 0; mt < 2; mt++) {
    int row = q0 + wave * 32 + mt * 16 + l15;
    #pragma unroll
    for (int ks = 0; ks < 4; ks++)
      qf[mt][ks] = *(const bf16x8*)&Qb[(size_t)row * rs + ks * 32 + quad * 8];
  }

  // DMA staging pointers (swizzle folded into global address, LDS dest = base+lane*16)
  const bf16* kp[4]; const f16* vp[4];
  bf16* kl[4]; f16* vl[4];
  #pragma unroll
  for (int t = 0; t < 4; t++) {
    int keyl = wave * 16 + t * 4 + (lane >> 4);
    int ck = (lane & 15) ^ (4 * (t & 1) + (lane >> 4));  // keyl&7 = 4*(t&1)+(lane>>4)
    kp[t] = Kb + (size_t)keyl * rs + ck * 8;
    kl[t] = &Kl[(wave * 16 + t * 4) * 128];
    int dl = wave * 32 + t * 8 + (lane >> 3);
    int g = ((lane & 7) - (dl & 7)) & 7;  // source 8-key granule for LDS slot lane&7
    vp[t] = Vgb + (size_t)dl * 2048 + g * 8;
    vl[t] = &Vt[(wave * 32 + t * 8) * 64];
  }

  f32x4 oacc[2][8] = {};   // O: [mt][no], row=quad*4+r=qrow(mod16), col=l15=d(mod16)
  float mst[2] = {MASKV, MASKV}, lst[2] = {0.f, 0.f};

  const int nkt = 2 * qt + 2;
  const int myrow_hi = q0 + wave * 32 + 31;
  for (int kt = 0; kt < nkt; kt++) {
    const int k0 = kt * 64;
    __syncthreads();  // previous tile fully consumed
    #pragma unroll
    for (int t = 0; t < 4; t++) { GLD16(kp[t], kl[t]); kp[t] += 64 * rs; }
    #pragma unroll
    for (int t = 0; t < 4; t++) { GLD16(vp[t], vl[t]); vp[t] += 64; }
    __syncthreads();  // vmcnt drained before barrier -> tiles ready

    if (k0 > myrow_hi) continue;  // wave fully masked

    // S^T = K·Q^T : s[mt][nt], nt = key16 chunk
    f32x4 s[2][4] = {};
    #pragma unroll
    for (int ks = 0; ks < 4; ks++) {
      #pragma unroll
      for (int nt = 0; nt < 4; nt++) {
        bf16x8 kf = *(const bf16x8*)&Kl[(nt * 16 + l15) * 128 +
                                        (((ks * 4 + quad) ^ (l15 & 7)) * 8)];
        s[0][nt] = MFMA16(kf, qf[0][ks], s[0][nt]);
        s[1][nt] = MFMA16(kf, qf[1][ks], s[1][nt]);
      }
    }
    // causal mask: key > qrow (only last two tiles touch the diagonal)
    if (kt >= nkt - 2) {
      #pragma unroll
      for (int mt = 0; mt < 2; mt++) {
        int qrow = q0 + wave * 32 + mt * 16 + l15;
        #pragma unroll
        for (int nt = 0; nt < 4; nt++) {
          int keyb = k0 + nt * 16 + quad * 4;
          #pragma unroll
          for (int r = 0; r < 4; r++)
            if (keyb + r > qrow) s[mt][nt][r] = MASKV;
        }
      }
    }
    // online softmax: per-lane scalar stats (lane owns q-row = l15 per mt);
    // xor-16/32 reduction makes stats uniform across the 4 quads of a q-row.
    f16x4 pa[2][4];
    #pragma unroll
    for (int mt = 0; mt < 2; mt++) {
      float mloc = MASKV;
      #pragma unroll
      for (int nt = 0; nt < 4; nt++)
        #pragma unroll
        for (int r = 0; r < 4; r++) mloc = fmaxf(mloc, s[mt][nt][r]);
      mloc = fmaxf(mloc, __shfl_xor(mloc, 16));
      mloc = fmaxf(mloc, __shfl_xor(mloc, 32));
      float mnew = fmaxf(mst[mt], mloc);
      float alpha = exp2f(mst[mt] - mnew);
      float rsum = 0.f;
      #pragma unroll
      for (int nt = 0; nt < 4; nt++)
        #pragma unroll
        for (int r = 0; r < 4; r++) {
          float p = exp2f(s[mt][nt][r] - mnew);
          s[mt][nt][r] = p;
          rsum += p;
        }
      rsum += __shfl_xor(rsum, 16);
      rsum += __shfl_xor(rsum, 32);
      lst[mt] = lst[mt] * alpha + rsum;
      mst[mt] = mnew;
      // redistribute alpha from l15-indexing to row-indexing (quad*4+r)
      float ar[4];
      #pragma unroll
      for (int r = 0; r < 4; r++) ar[r] = __shfl(alpha, quad * 4 + r);
      #pragma unroll
      for (int no = 0; no < 8; no++)
        #pragma unroll
        for (int r = 0; r < 4; r++) oacc[mt][no][r] *= ar[r];
      #pragma unroll
      for (int nt = 0; nt < 4; nt++) {
        f16x4 p4;
        #pragma unroll
        for (int r = 0; r < 4; r++) p4[r] = (f16)s[mt][nt][r];
        pa[mt][nt] = p4;
      }
    }
    // O += P·V : A = pa (P[m=qrow on l15][k=key quad*4+r]), B = vf
    // (V[k=key quad*4+i][n=d on l15]) -> D row=quad*4+r=qrow, col=l15=d.
    #pragma unroll
    for (int nt = 0; nt < 4; nt++) {
      #pragma unroll
      for (int no = 0; no < 8; no++) {
        f16x4 vf = *(const f16x4*)&Vt[(no * 16 + l15) * 64 +
                                      (((nt * 4 + quad) + 2 * (l15 & 7)) & 15) * 4];
        oacc[0][no] = MFMA16F16(pa[0][nt], vf, oacc[0][no]);
        oacc[1][no] = MFMA16F16(pa[1][nt], vf, oacc[1][no]);
      }
    }
  }

  // epilogue: coalesced row-major writes; linv redistributed like alpha
  #pragma unroll
  for (int mt = 0; mt < 2; mt++) {
    float linv = 1.0f / lst[mt];
    float lr[4];
    #pragma unroll
    for (int r = 0; r < 4; r++) lr[r] = __shfl(linv, quad * 4 + r);
    int row = q0 + wave * 32 + mt * 16 + quad * 4;
    #pragma unroll
    for (int no = 0; no < 8; no++) {
      int col = h * 128 + no * 16 + l15;
      #pragma unroll
      for (int r = 0; r < 4; r++)
        Obf[(size_t)(b * 2048 + row + r) * 2048 + col] = (bf16)(oacc[mt][no][r] * lr[r]);
    }
  }
}

extern "C" void kernel_launch(void* const* d_in, const int* in_sizes, int n_in,
                              void* d_out, int out_size, void* d_ws, size_t ws_size,
                              hipStream_t stream) {
  const float* x  = (const float*)d_in[0];
  // d_in[1] = mask: always causal tril; handled analytically.
  const float* Wq = (const float*)d_in[2];
  const float* Wk = (const float*)d_in[3];
  const float* Wv = (const float*)d_in[4];
  const float* Wo = (const float*)d_in[5];
  float* out = (float*)d_out;

  // workspace layout (2-byte elements)
  bf16* Xb    = (bf16*)d_ws;           // 4096x2048
  bf16* Wqkvt = Xb + 8388608;          // 3072x2048 (transposed, fused Q|K|V)
  bf16* Wot   = Wqkvt + 6291456;       // 2048x2048 (transposed)
  bf16* QKV   = Wot + 4194304;         // 4096x3072
  bf16* Obf   = QKV + 12582912;        // 4096x2048
  f16*  Vg    = (f16*)(Obf + 8388608); // 8 x 128 x 2048 (V^T per (b,kvh), f16)
  // total 83,886,080 bytes

  const float qscale = (float)(0.08838834764831845 * 1.4426950408889634);

  cast_f32_bf16<<<8192, 256, 0, stream>>>(x, Xb, 2097152);
  dim3 tb(32, 8);
  transpose_cast<<<dim3(64, 64), tb, 0, stream>>>(Wq, Wqkvt, 2048, 2048, 0, qscale);
  transpose_cast<<<dim3(16, 64), tb, 0, stream>>>(Wk, Wqkvt, 512, 2048, 2048, 1.0f);
  transpose_cast<<<dim3(16, 64), tb, 0, stream>>>(Wv, Wqkvt, 512, 2048, 2560, 1.0f);
  transpose_cast<<<dim3(64, 64), tb, 0, stream>>>(Wo, Wot, 2048, 2048, 0, 1.0f);

  gemm_bt<bf16><<<dim3(24, 32), 256, 0, stream>>>(Xb, Wqkvt, QKV, 4096, 3072, 2048);
  transpose_v<<<dim3(64, 4, 8), tb, 0, stream>>>(QKV, Vg);
  gqa_attn<<<512, 256, 0, stream>>>(QKV, Vg, Obf);
  gemm_bt<float><<<dim3(16, 32), 256, 0, stream>>>(Obf, Wot, out, 4096, 2048, 2048);
}